// Round 6
// baseline (642.137 us; speedup 1.0000x reference)
//
#include <hip/hip_runtime.h>

// Problem constants (match reference)
#define Bsz 8
#define Ssz 2048
#define PLM 768
#define Gd  256
#define N_WM 50000
#define E_WM 800000
#define N_F  16384   // B*S
#define E_F  131072
#define Kc   4

typedef unsigned short ushort_t;
typedef unsigned int uint_t;
typedef short short8 __attribute__((ext_vector_type(8)));
typedef float f32x4 __attribute__((ext_vector_type(4)));

// RNE float -> bf16 bits
__device__ __forceinline__ ushort_t f2bf(float f) {
    union { float f; unsigned int u; } v; v.f = f;
    unsigned int r = (v.u + 0x7fffu + ((v.u >> 16) & 1u)) >> 16;
    return (ushort_t)r;
}
__device__ __forceinline__ float bf2f(ushort_t b) {
    union { unsigned int u; float f; } v; v.u = ((unsigned int)b) << 16;
    return v.f;
}
__device__ __forceinline__ float4 bf4f(ushort4 u) {
    return make_float4(bf2f(u.x), bf2f(u.y), bf2f(u.z), bf2f(u.w));
}

// async global->LDS, 16B per lane; LDS dest must be wave-uniform base
__device__ __forceinline__ void gl2lds16(const ushort_t* g, ushort_t* l) {
    __builtin_amdgcn_global_load_lds(
        (const __attribute__((address_space(1))) unsigned int*)g,
        (__attribute__((address_space(3))) unsigned int*)l, 16, 0, 0);
}

// WM slice-major layout: h_s[8][N_WM][32] bf16 (slice s = cols [32s,32s+32))
#define NSL 8
#define SLW 32

// ---------------------------------------------------------------------------
// fused one-time conversions
// ---------------------------------------------------------------------------
__device__ __forceinline__ void cvt4(const float* __restrict__ in,
                                     ushort_t* __restrict__ out, int i, int n4) {
    if (i < n4) {
        float4 v = ((const float4*)in)[i];
        ushort4 u;
        u.x = f2bf(v.x); u.y = f2bf(v.y); u.z = f2bf(v.z); u.w = f2bf(v.w);
        ((ushort4*)out)[i] = u;
    }
}

// fp32 [nrows,256] -> slice-major bf16 [8][nrows][32]
__device__ __forceinline__ void cvt4_sm(const float* __restrict__ in,
                                        ushort_t* __restrict__ out, int i, int n4,
                                        int nrows) {
    if (i < n4) {
        float4 v = ((const float4*)in)[i];
        int flat = i * 4;
        int node = flat >> 8, c = flat & 255;
        int s = c >> 5, cc = c & 31;
        ushort4 u;
        u.x = f2bf(v.x); u.y = f2bf(v.y); u.z = f2bf(v.z); u.w = f2bf(v.w);
        *(ushort4*)&out[((size_t)s * nrows + node) * SLW + cc] = u;
    }
}

// one 64x64 tile of W[k][n] -> Wt[n][k], via padded LDS
__device__ __forceinline__ void wtx_tile(const float* __restrict__ W,
                                         ushort_t* __restrict__ Wt,
                                         int K, int N, int tile,
                                         ushort_t (*sm)[65]) {
    int kt = K >> 6;
    int k0 = (tile % kt) << 6;
    int n0 = (tile / kt) << 6;
    int t = threadIdx.x;
    int tr = t >> 6, tc = t & 63;
#pragma unroll
    for (int p = 0; p < 16; ++p) {
        int k = p * 4 + tr;
        sm[k][tc] = f2bf(W[(size_t)(k0 + k) * N + n0 + tc]);
    }
    __syncthreads();
#pragma unroll
    for (int p = 0; p < 16; ++p) {
        int n = p * 4 + tr;
        Wt[(size_t)(n0 + n) * K + k0 + tc] = sm[tc][n];
    }
}

// block ranges: 12500 cvt wm_x(slice-major) | 12288 cvt text | 1 extra
//             | 16 wm1 | 16 wm2 | 16 fs1 | 16 fs2 | 64 fc1 | 240 fc3
// total 25157 blocks
__global__ void conv_all(const float* __restrict__ wm_x, const float* __restrict__ text,
                         const float* __restrict__ extra,
                         const float* __restrict__ W1, const float* __restrict__ W2,
                         const float* __restrict__ W3, const float* __restrict__ W4,
                         const float* __restrict__ W5, const float* __restrict__ W6,
                         ushort_t* __restrict__ Xb, ushort_t* __restrict__ Tx,
                         ushort_t* __restrict__ Exb,
                         ushort_t* __restrict__ T1, ushort_t* __restrict__ T2,
                         ushort_t* __restrict__ T3, ushort_t* __restrict__ T4,
                         ushort_t* __restrict__ T5, ushort_t* __restrict__ T6) {
    __shared__ ushort_t sm[64][65];
    int b = blockIdx.x, t = threadIdx.x;
    if (b < 12500) { cvt4_sm(wm_x, Xb, b * 256 + t, 3200000, N_WM); return; }
    b -= 12500;
    if (b < 12288) { cvt4(text, Tx, b * 256 + t, 3145728); return; }
    b -= 12288;
    if (b < 1) { cvt4(extra, Exb, t, 128); return; }
    b -= 1;
    if (b < 16) { wtx_tile(W1, T1, 256, 256, b, sm); return; }
    b -= 16;
    if (b < 16) { wtx_tile(W2, T2, 256, 256, b, sm); return; }
    b -= 16;
    if (b < 16) { wtx_tile(W3, T3, 256, 256, b, sm); return; }
    b -= 16;
    if (b < 16) { wtx_tile(W4, T4, 256, 256, b, sm); return; }
    b -= 16;
    if (b < 64) { wtx_tile(W5, T5, 1024, 256, b, sm); return; }
    b -= 64;
    wtx_tile(W6, T6, 1280, 768, b, sm);
}

// ---------------------------------------------------------------------------
// CSR build v2: 2-level LDS-atomic counting sort. NO global atomics.
// ---------------------------------------------------------------------------
#define WM_P 512
#define WM_CH 1563          // ceil(E_WM/WM_P)
#define WM_SHIFT 8
#define FS_P 128
#define FS_CH 1024          // E_F/FS_P exact
#define FS_SHIFT 6

__global__ __launch_bounds__(256) void csr_p1(const int* __restrict__ wm_dst,
                                              const int* __restrict__ f_dst,
                                              int* __restrict__ Cwm,
                                              int* __restrict__ Cfs) {
    __shared__ int hist[256];
    int b = blockIdx.x, t = threadIdx.x;
    hist[t] = 0; __syncthreads();
    if (b < WM_P) {
        int e0 = b * WM_CH, e1 = e0 + WM_CH; if (e1 > E_WM) e1 = E_WM;
        for (int e = e0 + t; e < e1; e += 256)
            atomicAdd(&hist[wm_dst[e] >> WM_SHIFT], 1);
        __syncthreads();
        Cwm[b * 256 + t] = hist[t];
    } else {
        int p = b - WM_P;
        int e0 = p * FS_CH, e1 = e0 + FS_CH;
        for (int e = e0 + t; e < e1; e += 256)
            atomicAdd(&hist[f_dst[e] >> FS_SHIFT], 1);
        __syncthreads();
        Cfs[p * 256 + t] = hist[t];
    }
}

__global__ __launch_bounds__(256) void csr_p2a(int* __restrict__ Cwm, int* __restrict__ BTwm,
                                               int* __restrict__ Cfs, int* __restrict__ BTfs) {
    __shared__ int sm[256];
    int b = blockIdx.x, t = threadIdx.x;
    int* C; int* BT; int P; int bk;
    if (b < 256) { C = Cwm; BT = BTwm; P = WM_P; bk = b; }
    else         { C = Cfs; BT = BTfs; P = FS_P; bk = b - 256; }
    int half = P >> 1;
    int v0 = 0, v1 = 0;
    if (t < half) { v0 = C[(2 * t) * 256 + bk]; v1 = C[(2 * t + 1) * 256 + bk]; }
    int s = v0 + v1;
    sm[t] = s; __syncthreads();
#pragma unroll
    for (int st = 1; st < 256; st <<= 1) {
        int x = (t >= st) ? sm[t - st] : 0;
        __syncthreads();
        sm[t] += x;
        __syncthreads();
    }
    int ex = sm[t] - s;
    if (t < half) {
        C[(2 * t) * 256 + bk] = ex;
        C[(2 * t + 1) * 256 + bk] = ex + v0;
    }
    if (t == 255) BT[bk] = sm[255];
}

__global__ __launch_bounds__(256) void csr_p2b(const int* __restrict__ BTwm,
                                               int* __restrict__ BSwm,
                                               const int* __restrict__ BTfs,
                                               int* __restrict__ BSfs) {
    __shared__ int sm[256];
    int t = threadIdx.x;
    const int* BT = blockIdx.x ? BTfs : BTwm;
    int* BS = blockIdx.x ? BSfs : BSwm;
    int E = blockIdx.x ? E_F : E_WM;
    int v = BT[t];
    sm[t] = v; __syncthreads();
#pragma unroll
    for (int st = 1; st < 256; st <<= 1) {
        int x = (t >= st) ? sm[t - st] : 0;
        __syncthreads();
        sm[t] += x;
        __syncthreads();
    }
    BS[t] = sm[t] - v;
    if (t == 255) BS[256] = E;
}

__global__ __launch_bounds__(256) void csr_p3(const int* __restrict__ wm_src,
                                              const int* __restrict__ wm_dst,
                                              const int* __restrict__ Cwm,
                                              const int* __restrict__ BSwm,
                                              int2* __restrict__ SEwm,
                                              const int* __restrict__ f_src,
                                              const int* __restrict__ f_dst,
                                              const int* __restrict__ Cfs,
                                              const int* __restrict__ BSfs,
                                              int2* __restrict__ SEfs) {
    __shared__ int cur[256];
    int b = blockIdx.x, t = threadIdx.x;
    if (b < WM_P) {
        cur[t] = Cwm[b * 256 + t] + BSwm[t];
        __syncthreads();
        int e0 = b * WM_CH, e1 = e0 + WM_CH; if (e1 > E_WM) e1 = E_WM;
        for (int e = e0 + t; e < e1; e += 256) {
            int d = wm_dst[e], s = wm_src[e];
            int pos = atomicAdd(&cur[d >> WM_SHIFT], 1);
            SEwm[pos] = make_int2(s, d);
        }
    } else {
        int p = b - WM_P;
        cur[t] = Cfs[p * 256 + t] + BSfs[t];
        __syncthreads();
        int e0 = p * FS_CH, e1 = e0 + FS_CH;
        for (int e = e0 + t; e < e1; e += 256) {
            int d = f_dst[e], s = f_src[e];
            int pos = atomicAdd(&cur[d >> FS_SHIFT], 1);
            SEfs[pos] = make_int2(s, d);
        }
    }
}

__global__ __launch_bounds__(256) void csr_p4(const int2* __restrict__ SEwm,
                                              const int* __restrict__ BSwm,
                                              int* __restrict__ wm_off,
                                              int* __restrict__ wm_bkt,
                                              const int2* __restrict__ SEfs,
                                              const int* __restrict__ BSfs,
                                              int* __restrict__ fs_off,
                                              int* __restrict__ fs_bkt) {
    __shared__ int cnt[256];
    __shared__ int sm[256];
    int ob = blockIdx.x, t = threadIdx.x;
    const int2* SE; const int* BS; int* off; int* bkt;
    int b, nb0, n, E, bw;
    if (ob < 256) { SE = SEwm; BS = BSwm; off = wm_off; bkt = wm_bkt;
                    b = ob; nb0 = b << WM_SHIFT; n = N_WM; E = E_WM; bw = 256; }
    else          { SE = SEfs; BS = BSfs; off = fs_off; bkt = fs_bkt;
                    b = ob - 256; nb0 = b << FS_SHIFT; n = N_F; E = E_F; bw = 64; }
    int e0 = BS[b], e1 = BS[b + 1];
    cnt[t] = 0; __syncthreads();
    for (int e = e0 + t; e < e1; e += 256)
        atomicAdd(&cnt[SE[e].y - nb0], 1);
    __syncthreads();
    int v = cnt[t];
    sm[t] = v; __syncthreads();
#pragma unroll
    for (int st = 1; st < 256; st <<= 1) {
        int x = (t >= st) ? sm[t - st] : 0;
        __syncthreads();
        sm[t] += x;
        __syncthreads();
    }
    int ex = sm[t] - v;
    if (t < bw && nb0 + t < n) off[nb0 + t] = e0 + ex;
    if (b == 0 && t == 0) off[n] = E;
    __syncthreads();
    cnt[t] = e0 + ex;        // cursors
    __syncthreads();
    for (int e = e0 + t; e < e1; e += 256) {
        int2 sd = SE[e];
        int pos = atomicAdd(&cnt[sd.y - nb0], 1);
        bkt[pos] = sd.x;
    }
}

// ---------------------------------------------------------------------------
// WM aggregate, slice-resident v2: h/hm slice-major [8][n][32] bf16.
// blockIdx&7 = slice -> pinned XCD; slice table 3.2MB -> L2-resident.
// ONE WAVE PER (slice,node): 8 lanes x ushort4 (8B) per 64B row, 8 edges
// per load instruction, 2-deep batch (16 edges in flight). No cross-node
// divergence. Butterfly shfl_xor(8/16/32) reduces the 8 edge-slots.
// ---------------------------------------------------------------------------
__global__ __launch_bounds__(256) void aggregate_sliced(
        const ushort_t* __restrict__ h, const int* __restrict__ off,
        const int* __restrict__ bucket, ushort_t* __restrict__ hm, int n) {
    int bid = blockIdx.x;
    int s = bid & 7, nb = bid >> 3;
    int wave = threadIdx.x >> 6;
    int lane = threadIdx.x & 63;
    int i = nb * 4 + wave;
    if (i >= n) return;
    int g = lane >> 3;               // edge slot 0..7
    int li = lane & 7;               // column slot (ushort4 units, 8 per row)
    const ushort4* hp = (const ushort4*)(h + (size_t)s * n * SLW);
    ushort4* op = (ushort4*)(hm + (size_t)s * n * SLW);
    int s0 = off[i], s1 = off[i + 1];
    float ax = 0.f, ay = 0.f, az = 0.f, aw = 0.f;
    int j = s0;
    // 16 edges per iteration: 2 independent gathers in flight
    for (; j + 16 <= s1; j += 16) {
        int b0 = bucket[j + g];
        int b1 = bucket[j + 8 + g];
        ushort4 r0 = hp[(size_t)b0 * 8 + li];
        ushort4 r1 = hp[(size_t)b1 * 8 + li];
        float4 v0 = bf4f(r0), v1 = bf4f(r1);
        ax += v0.x + v1.x; ay += v0.y + v1.y;
        az += v0.z + v1.z; aw += v0.w + v1.w;
    }
    for (; j + 8 <= s1; j += 8) {
        int b0 = bucket[j + g];
        ushort4 r0 = hp[(size_t)b0 * 8 + li];
        float4 v0 = bf4f(r0);
        ax += v0.x; ay += v0.y; az += v0.z; aw += v0.w;
    }
    if (j + g < s1) {
        int b0 = bucket[j + g];
        ushort4 r0 = hp[(size_t)b0 * 8 + li];
        float4 v0 = bf4f(r0);
        ax += v0.x; ay += v0.y; az += v0.z; aw += v0.w;
    }
    // reduce across the 8 edge slots (lanes with same li)
#pragma unroll
    for (int m = 8; m < 64; m <<= 1) {
        ax += __shfl_xor(ax, m, 64);
        ay += __shfl_xor(ay, m, 64);
        az += __shfl_xor(az, m, 64);
        aw += __shfl_xor(aw, m, 64);
    }
    if (g == 0) {
        float4 dv = bf4f(hp[(size_t)i * 8 + li]);
        ushort4 u;
        u.x = f2bf(ax + dv.x); u.y = f2bf(ay + dv.y);
        u.z = f2bf(az + dv.z); u.w = f2bf(aw + dv.w);
        op[(size_t)i * 8 + li] = u;
    }
}

// ---------------------------------------------------------------------------
// FSTM aggregate (row-major, unchanged): hm[i] = h[i] + sum h[bucket[j]]
// ---------------------------------------------------------------------------
__global__ void aggregate_kernel(const ushort_t* __restrict__ h,
                                 const int* __restrict__ off,
                                 const int* __restrict__ bucket,
                                 ushort_t* __restrict__ hm, int n) {
    int i = blockIdx.x * 4 + (threadIdx.x >> 6);
    if (i >= n) return;
    int lane = threadIdx.x & 63;
    int s0 = off[i], s1 = off[i + 1];
    const ushort4* hp = (const ushort4*)h;   // 64 ushort4 per row
    float4 acc = bf4f(hp[(size_t)i * 64 + lane]);
    int j = s0;
    for (; j + 8 <= s1; j += 8) {
        int bb[8];
#pragma unroll
        for (int q = 0; q < 8; ++q) bb[q] = bucket[j + q];
        ushort4 rr[8];
#pragma unroll
        for (int q = 0; q < 8; ++q) rr[q] = hp[(size_t)bb[q] * 64 + lane];
#pragma unroll
        for (int q = 0; q < 8; ++q) {
            float4 v = bf4f(rr[q]);
            acc.x += v.x; acc.y += v.y; acc.z += v.z; acc.w += v.w;
        }
    }
    for (; j < s1; ++j) {
        float4 v = bf4f(hp[(size_t)bucket[j] * 64 + lane]);
        acc.x += v.x; acc.y += v.y; acc.z += v.z; acc.w += v.w;
    }
    ushort4 u;
    u.x = f2bf(acc.x); u.y = f2bf(acc.y); u.z = f2bf(acc.z); u.w = f2bf(acc.w);
    ((ushort4*)hm)[(size_t)i * 64 + lane] = u;
}

// ---------------------------------------------------------------------------
// tmp[i] = sum_k table[token2nodepos[i,k]+2]   (bf16 table, fp32 accumulate)
// ---------------------------------------------------------------------------
__global__ void tmp_kernel(const ushort_t* __restrict__ gemb,
                           const ushort_t* __restrict__ extra,
                           const int* __restrict__ t2np,
                           ushort_t* __restrict__ D) {
    int i = blockIdx.x * 4 + (threadIdx.x >> 6);
    int lane = threadIdx.x & 63;
    float4 s = make_float4(0.f, 0.f, 0.f, 0.f);
#pragma unroll
    for (int k = 0; k < Kc; ++k) {
        int idx = t2np[i * Kc + k] + 2;
        const ushort4* row = (idx < 2) ? (const ushort4*)(extra + (size_t)idx * Gd)
                                       : (const ushort4*)(gemb + (size_t)(idx - 2) * Gd);
        float4 v = bf4f(row[lane]);
        s.x += v.x; s.y += v.y; s.z += v.z; s.w += v.w;
    }
    ushort4 u;
    u.x = f2bf(s.x); u.y = f2bf(s.y); u.z = f2bf(s.z); u.w = f2bf(s.w);
    ((ushort4*)D)[(size_t)i * 64 + lane] = u;
}

// ---------------------------------------------------------------------------
// row gather (bf16): F[i] = E[ids[i]]
// ---------------------------------------------------------------------------
__global__ void gather_kernel(const ushort_t* __restrict__ Ein,
                              const int* __restrict__ ids,
                              ushort_t* __restrict__ F) {
    int i = blockIdx.x * 4 + (threadIdx.x >> 6);
    int lane = threadIdx.x & 63;
    ((ushort4*)F)[(size_t)i * 64 + lane] =
        ((const ushort4*)Ein)[(size_t)ids[i] * 64 + lane];
}

// ---------------------------------------------------------------------------
// bf16 MFMA GEMM, templated BM x BN (BK=64), lds-dma staging, XCD swizzle,
// T2 source-pre-swizzle bank-conflict fix.
// MODE 0: A = p0[row][k] row-major, rowlen K
// MODE 1: A slice-major [8][M][32]: elem (row,k) at p0[((k>>5)*M+row)*32+(k&31)]
// MODE 2: A = k<256 ? p0 : p1(k-256) rowlen 768        (tmp|text), K=1024
// MODE 3: A = k<768 ? p0 : k<1024 ? p1 : p2            (text|tmp|temporal), K=1280
// OUTBF: 1 -> bf16 C, 0 -> fp32 C.  OUTSM: 1 -> C slice-major [8][M][32]
// ---------------------------------------------------------------------------
#define TBK 64
#define GBM 64
#define GBN 128

__device__ __forceinline__ void xcd_swizzle(int& bx, int& by) {
    int gx = gridDim.x;
    int nwg = gx * gridDim.y;
    int orig = by * gx + bx;
    int q = nwg >> 3, r = nwg & 7;
    int xcd = orig & 7, loc = orig >> 3;
    int wg = (xcd < r ? xcd * (q + 1) : r * (q + 1) + (xcd - r) * q) + loc;
    bx = wg % gx;
    by = wg / gx;
}

template <int MODE, int OUTBF, int OUTSM, int BM, int BN>
__global__ __launch_bounds__(256) void mfma_gemm(
    const ushort_t* __restrict__ p0, const ushort_t* __restrict__ p1,
    const ushort_t* __restrict__ p2, const ushort_t* __restrict__ Wt,
    const float* __restrict__ bias, void* __restrict__ Cv,
    int M, int N, int K, int relu) {
    constexpr int MR = BM / 32;          // m-frags per wave (2 waves in M)
    constexpr int NR = BN / 32;          // n-frags per wave (2 waves in N)
    constexpr int A_IT = (BM * TBK) / 2048;
    constexpr int B_IT = (BN * TBK) / 2048;
    __shared__ ushort_t As[BM * TBK];    // [row][k] linear (lds-dma dest)
    __shared__ ushort_t Bs[BN * TBK];    // [col][k] linear

    int tid  = threadIdx.x;
    int lane = tid & 63;
    int wave = tid >> 6;
    int wm = (wave >> 1) * (BM / 2), wn = (wave & 1) * (BN / 2);
    int bx = blockIdx.x, by = blockIdx.y;
    xcd_swizzle(bx, by);
    int row0 = by * BM, col0 = bx * BN;
    int l15 = lane & 15, l4 = lane >> 4;

    f32x4 acc[MR][NR];
#pragma unroll
    for (int i = 0; i < MR; ++i)
#pragma unroll
        for (int j = 0; j < NR; ++j)
            acc[i][j] = (f32x4){0.f, 0.f, 0.f, 0.f};

    for (int k0 = 0; k0 < K; k0 += TBK) {
        // ---- stage A via lds-dma (pre-swizzled global source) ----
#pragma unroll
        for (int it = 0; it < A_IT; ++it) {
            int eb = it * 2048 + wave * 512;   // wave-uniform elem base
            int le = eb + lane * 8;
            int r  = le >> 6;
            int kl = (le ^ ((r & 7) << 3)) & 63;   // T2 source pre-swizzle (8-aligned)
            int grow = row0 + r; if (grow > M - 1) grow = M - 1;
            int gk = k0 + kl;
            const ushort_t* gp;
            if (MODE == 0)
                gp = p0 + (size_t)grow * K + gk;
            else if (MODE == 1)
                gp = p0 + ((size_t)(gk >> 5) * M + grow) * SLW + (gk & 31);
            else if (MODE == 2)
                gp = (gk < 256) ? p0 + (size_t)grow * 256 + gk
                                : p1 + (size_t)grow * 768 + (gk - 256);
            else
                gp = (gk < 768) ? p0 + (size_t)grow * 768 + gk
                   : (gk < 1024) ? p1 + (size_t)grow * 256 + (gk - 768)
                                 : p2 + (size_t)grow * 256 + (gk - 1024);
            gl2lds16(gp, &As[eb]);
        }
        // ---- stage B via lds-dma ----
#pragma unroll
        for (int it = 0; it < B_IT; ++it) {
            int eb = it * 2048 + wave * 512;
            int le = eb + lane * 8;
            int nl = le >> 6;
            int kl = (le ^ ((nl & 7) << 3)) & 63;
            const ushort_t* gp = Wt + (size_t)(col0 + nl) * K + k0 + kl;
            gl2lds16(gp, &Bs[eb]);
        }
        __syncthreads();

#pragma unroll
        for (int ks = 0; ks < TBK; ks += 32) {
            short8 af[MR], bfr[NR];
#pragma unroll
            for (int mi = 0; mi < MR; ++mi) {
                int row = wm + mi * 16 + l15;
                int col = (ks + l4 * 8) ^ ((row & 7) << 3);
                af[mi] = *(const short8*)&As[row * TBK + col];
            }
#pragma unroll
            for (int ni = 0; ni < NR; ++ni) {
                int row = wn + ni * 16 + l15;
                int col = (ks + l4 * 8) ^ ((row & 7) << 3);
                bfr[ni] = *(const short8*)&Bs[row * TBK + col];
            }
#pragma unroll
            for (int mi = 0; mi < MR; ++mi)
#pragma unroll
                for (int ni = 0; ni < NR; ++ni)
                    acc[mi][ni] = __builtin_amdgcn_mfma_f32_16x16x32_bf16(
                        af[mi], bfr[ni], acc[mi][ni], 0, 0, 0);
        }
        __syncthreads();
    }

    // ---- epilogue: bias (+relu); C/D layout col=lane&15, row=(lane>>4)*4+reg ----
#pragma unroll
    for (int ni = 0; ni < NR; ++ni) {
        int c = col0 + wn + ni * 16 + l15;
        float bv = bias[c];
#pragma unroll
        for (int mi = 0; mi < MR; ++mi) {
#pragma unroll
            for (int r = 0; r < 4; ++r) {
                int rr = row0 + wm + mi * 16 + l4 * 4 + r;
                if (rr < M) {
                    float v = acc[mi][ni][r] + bv;
                    if (relu) v = fmaxf(v, 0.f);
                    if (OUTBF) {
                        if (OUTSM)
                            ((ushort_t*)Cv)[((size_t)(c >> 5) * M + rr) * SLW + (c & 31)] = f2bf(v);
                        else
                            ((ushort_t*)Cv)[(size_t)rr * N + c] = f2bf(v);
                    } else {
                        ((float*)Cv)[(size_t)rr * N + c] = v;
                    }
                }
            }
        }
    }
}

// ---------------------------------------------------------------------------
extern "C" void kernel_launch(void* const* d_in, const int* in_sizes, int n_in,
                              void* d_out, int out_size, void* d_ws, size_t ws_size,
                              hipStream_t stream) {
    const float* text    = (const float*)d_in[0];   // [16384, 768]
    const float* wm_x    = (const float*)d_in[1];   // [50000, 256]
    const int*   wm_ei   = (const int*)d_in[2];     // [2, 800000]
    const int*   t2np    = (const int*)d_in[3];     // [16384, 4]
    const int*   f_ids   = (const int*)d_in[4];     // [16384]
    const int*   f_ei    = (const int*)d_in[5];     // [2, 131072]
    const float* extra   = (const float*)d_in[6];   // [2, 256]
    const float* wm_W1   = (const float*)d_in[7];
    const float* wm_b1   = (const float*)d_in[8];
    const float* wm_W2   = (const float*)d_in[9];
    const float* wm_b2   = (const float*)d_in[10];
    const float* fs_W1   = (const float*)d_in[11];
    const float* fs_b1   = (const float*)d_in[12];
    const float* fs_W2   = (const float*)d_in[13];
    const float* fs_b2   = (const float*)d_in[14];
    const float* fc1_W   = (const float*)d_in[15];  // [1024, 256]
    const float* fc1_b   = (const float*)d_in[16];
    const float* fc3_W   = (const float*)d_in[17];  // [1280, 768]
    const float* fc3_b   = (const float*)d_in[18];
    float* out = (float*)d_out;                     // [16384, 768]

    // ---- workspace layout (bf16 = ushort) ----
    ushort_t* Xb  = (ushort_t*)d_ws;            // [8][50000][32] slice-major (reused: h1)
    ushort_t* Ag  = Xb + 12800000;              // [8][50000][32] aggregate out / scratch
    ushort_t* Gm  = Ag + 12800000;              // [50000*256] gemb row-major (reused: F, H)
    ushort_t* Tx  = Gm + 12800000;              // [16384*768] text bf16
    ushort_t* Dt  = Tx + 12582912;              // [16384*256] tmp
    ushort_t* Ee  = Dt + 4194304;               // [16384*256] gte (reused: T)
    ushort_t* Wv  = Ee + 4194304;               // weights, transposed bf16
    ushort_t* wt_wm1 = Wv;                      //  65536
    ushort_t* wt_wm2 = wt_wm1 + 65536;          //  65536
    ushort_t* wt_fs1 = wt_wm2 + 65536;          //  65536
    ushort_t* wt_fs2 = wt_fs1 + 65536;          //  65536
    ushort_t* wt_fc1 = wt_fs2 + 65536;          //  262144
    ushort_t* wt_fc3 = wt_fc1 + 262144;         //  983040
    ushort_t* Exb    = wt_fc3 + 983040;         //  512
    // persistent CSR outputs
    int* wm_off = (int*)(Exb + 512);            // [N_WM+1]
    int* fs_off = wm_off + N_WM + 1;            // [N_F+1]
    int* wm_bkt = fs_off + N_F + 1;             // [E_WM]
    int* fs_bkt = wm_bkt + E_WM;                // [E_F]
    // CSR-build scratch overlaid on Ag (dead until first aggregate)
    int2* SEwm = (int2*)Ag;                     // [E_WM] int2 (6.4MB)
    int2* SEfs = SEwm + E_WM;                   // [E_F]  int2 (1.05MB)
    int*  Cwm  = (int*)(SEfs + E_F);            // [WM_P*256]
    int*  Cfs  = Cwm + WM_P * 256;              // [FS_P*256]
    int*  BTwm = Cfs + FS_P * 256;              // [256]
    int*  BTfs = BTwm + 256;                    // [256]
    int*  BSwm = BTfs + 256;                    // [257]
    int*  BSfs = BSwm + 257;                    // [257]

    ushort_t* h1 = Xb;                 // gemm1 out overwrites Xb (dead), slice-major
    ushort_t* F  = Gm;                 // gather out overwrites gemb (dead)
    ushort_t* H  = Gm + 4194304;
    ushort_t* T  = Ee;                 // fstm out overwrites Ee (dead)

    const int* wm_src = wm_ei;
    const int* wm_dst = wm_ei + E_WM;
    const int* f_src  = f_ei;
    const int* f_dst  = f_ei + E_F;

    dim3 blk(256);
    dim3 gW(Gd / GBN, (N_WM + GBM - 1) / GBM);   // 2 x 782
    dim3 gF(Gd / GBN, N_F / GBM);                // 2 x 256
    dim3 gO(PLM / GBN, N_F / GBM);               // 6 x 256
    const int gAggW = NSL * ((N_WM + 3) / 4);    // 8 x 12500 = 100000 (wave/node)

    // ===== CSR build (counting sort, LDS atomics only) =====
    csr_p1<<<WM_P + FS_P, blk, 0, stream>>>(wm_dst, f_dst, Cwm, Cfs);
    csr_p2a<<<512, blk, 0, stream>>>(Cwm, BTwm, Cfs, BTfs);
    csr_p2b<<<2, blk, 0, stream>>>(BTwm, BSwm, BTfs, BSfs);
    csr_p3<<<WM_P + FS_P, blk, 0, stream>>>(wm_src, wm_dst, Cwm, BSwm, SEwm,
                                            f_src, f_dst, Cfs, BSfs, SEfs);
    csr_p4<<<512, blk, 0, stream>>>(SEwm, BSwm, wm_off, wm_bkt,
                                    SEfs, BSfs, fs_off, fs_bkt);

    // ===== one-time conversions (fused) =====
    conv_all<<<25157, blk, 0, stream>>>(wm_x, text, extra,
                                        wm_W1, wm_W2, fs_W1, fs_W2, fc1_W, fc3_W,
                                        Xb, Tx, Exb,
                                        wt_wm1, wt_wm2, wt_fs1, wt_fs2,
                                        wt_fc1, wt_fc3);

    // ===== WM layer 1 (slice-major path) =====
    aggregate_sliced<<<gAggW, blk, 0, stream>>>(Xb, wm_off, wm_bkt, Ag, N_WM);
    mfma_gemm<1, 1, 1, GBM, GBN><<<gW, blk, 0, stream>>>(Ag, nullptr, nullptr, wt_wm1,
                                                         wm_b1, h1, N_WM, Gd, Gd, 1);
    // ===== WM layer 2 =====
    aggregate_sliced<<<gAggW, blk, 0, stream>>>(h1, wm_off, wm_bkt, Ag, N_WM);
    mfma_gemm<1, 1, 0, GBM, GBN><<<gW, blk, 0, stream>>>(Ag, nullptr, nullptr, wt_wm2,
                                                         wm_b2, Gm, N_WM, Gd, Gd, 1);
    // ===== tmp =====
    tmp_kernel<<<N_F / 4, blk, 0, stream>>>(Gm, Exb, t2np, Dt);
    // ===== fc1: Ee = concat(tmp, text) @ fc1_W + b =====
    mfma_gemm<2, 1, 0, GBM, GBN><<<gF, blk, 0, stream>>>(Dt, Tx, nullptr, wt_fc1,
                                                         fc1_b, Ee, N_F, Gd, Gd + PLM, 0);
    // ===== FSTM gather =====
    gather_kernel<<<N_F / 4, blk, 0, stream>>>(Ee, f_ids, F);
    // ===== FSTM layer 1 (row-major path) =====
    aggregate_kernel<<<N_F / 4, blk, 0, stream>>>(F, fs_off, fs_bkt, Ag, N_F);
    mfma_gemm<0, 1, 0, GBM, GBN><<<gF, blk, 0, stream>>>(Ag, nullptr, nullptr, wt_fs1,
                                                         fs_b1, H, N_F, Gd, Gd, 1);
    // ===== FSTM layer 2 =====
    aggregate_kernel<<<N_F / 4, blk, 0, stream>>>(H, fs_off, fs_bkt, Ag, N_F);
    mfma_gemm<0, 1, 0, GBM, GBN><<<gF, blk, 0, stream>>>(Ag, nullptr, nullptr, wt_fs2,
                                                         fs_b2, T, N_F, Gd, Gd, 1);
    // ===== fc3: out = concat(text, tmp, temporal) @ fc3_W + b (fp32 out) =====
    mfma_gemm<3, 0, 0, GBM, GBN><<<gO, blk, 0, stream>>>(Tx, Dt, T, wt_fc3, fc3_b,
                                                         out, N_F, PLM, PLM + 2 * Gd, 0);
}

// Round 7
// 523.481 us; speedup vs baseline: 1.2267x; 1.2267x over previous
//
#include <hip/hip_runtime.h>

// Problem constants (match reference)
#define Bsz 8
#define Ssz 2048
#define PLM 768
#define Gd  256
#define N_WM 50000
#define E_WM 800000
#define N_F  16384   // B*S
#define E_F  131072
#define Kc   4

typedef unsigned short ushort_t;
typedef unsigned int uint_t;
typedef short short8 __attribute__((ext_vector_type(8)));
typedef float f32x4 __attribute__((ext_vector_type(4)));

// RNE float -> bf16 bits
__device__ __forceinline__ ushort_t f2bf(float f) {
    union { float f; unsigned int u; } v; v.f = f;
    unsigned int r = (v.u + 0x7fffu + ((v.u >> 16) & 1u)) >> 16;
    return (ushort_t)r;
}
__device__ __forceinline__ float bf2f(ushort_t b) {
    union { unsigned int u; float f; } v; v.u = ((unsigned int)b) << 16;
    return v.f;
}
__device__ __forceinline__ float4 bf4f(ushort4 u) {
    return make_float4(bf2f(u.x), bf2f(u.y), bf2f(u.z), bf2f(u.w));
}

// async global->LDS, 16B per lane; LDS dest must be wave-uniform base
__device__ __forceinline__ void gl2lds16(const ushort_t* g, ushort_t* l) {
    __builtin_amdgcn_global_load_lds(
        (const __attribute__((address_space(1))) unsigned int*)g,
        (__attribute__((address_space(3))) unsigned int*)l, 16, 0, 0);
}

// WM slice-major layout: h_s[8][N_WM][32] bf16 (slice s = cols [32s,32s+32))
#define NSL 8
#define SLW 32

// ---------------------------------------------------------------------------
// fused one-time conversions
// ---------------------------------------------------------------------------
__device__ __forceinline__ void cvt4(const float* __restrict__ in,
                                     ushort_t* __restrict__ out, int i, int n4) {
    if (i < n4) {
        float4 v = ((const float4*)in)[i];
        ushort4 u;
        u.x = f2bf(v.x); u.y = f2bf(v.y); u.z = f2bf(v.z); u.w = f2bf(v.w);
        ((ushort4*)out)[i] = u;
    }
}

// fp32 [nrows,256] -> slice-major bf16 [8][nrows][32]
__device__ __forceinline__ void cvt4_sm(const float* __restrict__ in,
                                        ushort_t* __restrict__ out, int i, int n4,
                                        int nrows) {
    if (i < n4) {
        float4 v = ((const float4*)in)[i];
        int flat = i * 4;
        int node = flat >> 8, c = flat & 255;
        int s = c >> 5, cc = c & 31;
        ushort4 u;
        u.x = f2bf(v.x); u.y = f2bf(v.y); u.z = f2bf(v.z); u.w = f2bf(v.w);
        *(ushort4*)&out[((size_t)s * nrows + node) * SLW + cc] = u;
    }
}

// one 64x64 tile of W[k][n] -> Wt[n][k], via padded LDS
__device__ __forceinline__ void wtx_tile(const float* __restrict__ W,
                                         ushort_t* __restrict__ Wt,
                                         int K, int N, int tile,
                                         ushort_t (*sm)[65]) {
    int kt = K >> 6;
    int k0 = (tile % kt) << 6;
    int n0 = (tile / kt) << 6;
    int t = threadIdx.x;
    int tr = t >> 6, tc = t & 63;
#pragma unroll
    for (int p = 0; p < 16; ++p) {
        int k = p * 4 + tr;
        sm[k][tc] = f2bf(W[(size_t)(k0 + k) * N + n0 + tc]);
    }
    __syncthreads();
#pragma unroll
    for (int p = 0; p < 16; ++p) {
        int n = p * 4 + tr;
        Wt[(size_t)(n0 + n) * K + k0 + tc] = sm[tc][n];
    }
}

// block ranges: 12500 cvt wm_x(slice-major) | 12288 cvt text | 1 extra
//             | 16 wm1 | 16 wm2 | 16 fs1 | 16 fs2 | 64 fc1 | 240 fc3
// total 25157 blocks
__global__ void conv_all(const float* __restrict__ wm_x, const float* __restrict__ text,
                         const float* __restrict__ extra,
                         const float* __restrict__ W1, const float* __restrict__ W2,
                         const float* __restrict__ W3, const float* __restrict__ W4,
                         const float* __restrict__ W5, const float* __restrict__ W6,
                         ushort_t* __restrict__ Xb, ushort_t* __restrict__ Tx,
                         ushort_t* __restrict__ Exb,
                         ushort_t* __restrict__ T1, ushort_t* __restrict__ T2,
                         ushort_t* __restrict__ T3, ushort_t* __restrict__ T4,
                         ushort_t* __restrict__ T5, ushort_t* __restrict__ T6) {
    __shared__ ushort_t sm[64][65];
    int b = blockIdx.x, t = threadIdx.x;
    if (b < 12500) { cvt4_sm(wm_x, Xb, b * 256 + t, 3200000, N_WM); return; }
    b -= 12500;
    if (b < 12288) { cvt4(text, Tx, b * 256 + t, 3145728); return; }
    b -= 12288;
    if (b < 1) { cvt4(extra, Exb, t, 128); return; }
    b -= 1;
    if (b < 16) { wtx_tile(W1, T1, 256, 256, b, sm); return; }
    b -= 16;
    if (b < 16) { wtx_tile(W2, T2, 256, 256, b, sm); return; }
    b -= 16;
    if (b < 16) { wtx_tile(W3, T3, 256, 256, b, sm); return; }
    b -= 16;
    if (b < 16) { wtx_tile(W4, T4, 256, 256, b, sm); return; }
    b -= 16;
    if (b < 64) { wtx_tile(W5, T5, 1024, 256, b, sm); return; }
    b -= 64;
    wtx_tile(W6, T6, 1280, 768, b, sm);
}

// ---------------------------------------------------------------------------
// CSR build v2: 2-level LDS-atomic counting sort. NO global atomics.
// ---------------------------------------------------------------------------
#define WM_P 512
#define WM_CH 1563          // ceil(E_WM/WM_P)
#define WM_SHIFT 8
#define FS_P 128
#define FS_CH 1024          // E_F/FS_P exact
#define FS_SHIFT 6

__global__ __launch_bounds__(256) void csr_p1(const int* __restrict__ wm_dst,
                                              const int* __restrict__ f_dst,
                                              int* __restrict__ Cwm,
                                              int* __restrict__ Cfs) {
    __shared__ int hist[256];
    int b = blockIdx.x, t = threadIdx.x;
    hist[t] = 0; __syncthreads();
    if (b < WM_P) {
        int e0 = b * WM_CH, e1 = e0 + WM_CH; if (e1 > E_WM) e1 = E_WM;
        for (int e = e0 + t; e < e1; e += 256)
            atomicAdd(&hist[wm_dst[e] >> WM_SHIFT], 1);
        __syncthreads();
        Cwm[b * 256 + t] = hist[t];
    } else {
        int p = b - WM_P;
        int e0 = p * FS_CH, e1 = e0 + FS_CH;
        for (int e = e0 + t; e < e1; e += 256)
            atomicAdd(&hist[f_dst[e] >> FS_SHIFT], 1);
        __syncthreads();
        Cfs[p * 256 + t] = hist[t];
    }
}

__global__ __launch_bounds__(256) void csr_p2a(int* __restrict__ Cwm, int* __restrict__ BTwm,
                                               int* __restrict__ Cfs, int* __restrict__ BTfs) {
    __shared__ int sm[256];
    int b = blockIdx.x, t = threadIdx.x;
    int* C; int* BT; int P; int bk;
    if (b < 256) { C = Cwm; BT = BTwm; P = WM_P; bk = b; }
    else         { C = Cfs; BT = BTfs; P = FS_P; bk = b - 256; }
    int half = P >> 1;
    int v0 = 0, v1 = 0;
    if (t < half) { v0 = C[(2 * t) * 256 + bk]; v1 = C[(2 * t + 1) * 256 + bk]; }
    int s = v0 + v1;
    sm[t] = s; __syncthreads();
#pragma unroll
    for (int st = 1; st < 256; st <<= 1) {
        int x = (t >= st) ? sm[t - st] : 0;
        __syncthreads();
        sm[t] += x;
        __syncthreads();
    }
    int ex = sm[t] - s;
    if (t < half) {
        C[(2 * t) * 256 + bk] = ex;
        C[(2 * t + 1) * 256 + bk] = ex + v0;
    }
    if (t == 255) BT[bk] = sm[255];
}

__global__ __launch_bounds__(256) void csr_p2b(const int* __restrict__ BTwm,
                                               int* __restrict__ BSwm,
                                               const int* __restrict__ BTfs,
                                               int* __restrict__ BSfs) {
    __shared__ int sm[256];
    int t = threadIdx.x;
    const int* BT = blockIdx.x ? BTfs : BTwm;
    int* BS = blockIdx.x ? BSfs : BSwm;
    int E = blockIdx.x ? E_F : E_WM;
    int v = BT[t];
    sm[t] = v; __syncthreads();
#pragma unroll
    for (int st = 1; st < 256; st <<= 1) {
        int x = (t >= st) ? sm[t - st] : 0;
        __syncthreads();
        sm[t] += x;
        __syncthreads();
    }
    BS[t] = sm[t] - v;
    if (t == 255) BS[256] = E;
}

__global__ __launch_bounds__(256) void csr_p3(const int* __restrict__ wm_src,
                                              const int* __restrict__ wm_dst,
                                              const int* __restrict__ Cwm,
                                              const int* __restrict__ BSwm,
                                              int2* __restrict__ SEwm,
                                              const int* __restrict__ f_src,
                                              const int* __restrict__ f_dst,
                                              const int* __restrict__ Cfs,
                                              const int* __restrict__ BSfs,
                                              int2* __restrict__ SEfs) {
    __shared__ int cur[256];
    int b = blockIdx.x, t = threadIdx.x;
    if (b < WM_P) {
        cur[t] = Cwm[b * 256 + t] + BSwm[t];
        __syncthreads();
        int e0 = b * WM_CH, e1 = e0 + WM_CH; if (e1 > E_WM) e1 = E_WM;
        for (int e = e0 + t; e < e1; e += 256) {
            int d = wm_dst[e], s = wm_src[e];
            int pos = atomicAdd(&cur[d >> WM_SHIFT], 1);
            SEwm[pos] = make_int2(s, d);
        }
    } else {
        int p = b - WM_P;
        cur[t] = Cfs[p * 256 + t] + BSfs[t];
        __syncthreads();
        int e0 = p * FS_CH, e1 = e0 + FS_CH;
        for (int e = e0 + t; e < e1; e += 256) {
            int d = f_dst[e], s = f_src[e];
            int pos = atomicAdd(&cur[d >> FS_SHIFT], 1);
            SEfs[pos] = make_int2(s, d);
        }
    }
}

__global__ __launch_bounds__(256) void csr_p4(const int2* __restrict__ SEwm,
                                              const int* __restrict__ BSwm,
                                              int* __restrict__ wm_off,
                                              int* __restrict__ wm_bkt,
                                              const int2* __restrict__ SEfs,
                                              const int* __restrict__ BSfs,
                                              int* __restrict__ fs_off,
                                              int* __restrict__ fs_bkt) {
    __shared__ int cnt[256];
    __shared__ int sm[256];
    int ob = blockIdx.x, t = threadIdx.x;
    const int2* SE; const int* BS; int* off; int* bkt;
    int b, nb0, n, E, bw;
    if (ob < 256) { SE = SEwm; BS = BSwm; off = wm_off; bkt = wm_bkt;
                    b = ob; nb0 = b << WM_SHIFT; n = N_WM; E = E_WM; bw = 256; }
    else          { SE = SEfs; BS = BSfs; off = fs_off; bkt = fs_bkt;
                    b = ob - 256; nb0 = b << FS_SHIFT; n = N_F; E = E_F; bw = 64; }
    int e0 = BS[b], e1 = BS[b + 1];
    cnt[t] = 0; __syncthreads();
    for (int e = e0 + t; e < e1; e += 256)
        atomicAdd(&cnt[SE[e].y - nb0], 1);
    __syncthreads();
    int v = cnt[t];
    sm[t] = v; __syncthreads();
#pragma unroll
    for (int st = 1; st < 256; st <<= 1) {
        int x = (t >= st) ? sm[t - st] : 0;
        __syncthreads();
        sm[t] += x;
        __syncthreads();
    }
    int ex = sm[t] - v;
    if (t < bw && nb0 + t < n) off[nb0 + t] = e0 + ex;
    if (b == 0 && t == 0) off[n] = E;
    __syncthreads();
    cnt[t] = e0 + ex;        // cursors
    __syncthreads();
    for (int e = e0 + t; e < e1; e += 256) {
        int2 sd = SE[e];
        int pos = atomicAdd(&cnt[sd.y - nb0], 1);
        bkt[pos] = sd.x;
    }
}

// ---------------------------------------------------------------------------
// WM aggregate, slice-resident v3: h/hm slice-major [8][n][32] bf16.
// blockIdx&7 = slice -> pinned XCD; slice table 3.2MB -> L2-resident.
// lane = (node_local = lane>>3, li = lane&7): 8 lanes x ushort4 own one
// node's 64B row; wave carries 8 nodes, 1 edge/node/iter, 4-deep batched.
// NO cross-lane reduction, no shuffles; full 512B loads & stores.
// Divergence bounded by max-degree-of-8 (~22.6 vs mean 16).
// ---------------------------------------------------------------------------
__global__ __launch_bounds__(256) void aggregate_sliced(
        const ushort_t* __restrict__ h, const int* __restrict__ off,
        const int* __restrict__ bucket, ushort_t* __restrict__ hm, int n) {
    int bid = blockIdx.x;
    int s = bid & 7, grp = bid >> 3;          // 32 nodes per block (4 waves x 8)
    int wave = threadIdx.x >> 6;
    int lane = threadIdx.x & 63;
    int nl = lane >> 3;               // node slot 0..7
    int li = lane & 7;                // ushort4 column slot
    int i = grp * 32 + wave * 8 + nl;
    if (i >= n) i = n - 1;            // clamp: duplicate compute of last node (benign)
    const ushort4* hp = (const ushort4*)(h + (size_t)s * n * SLW);
    ushort4* op = (ushort4*)(hm + (size_t)s * n * SLW);
    int s0 = off[i], deg = off[i + 1] - s0;
    float4 acc = bf4f(hp[(size_t)i * 8 + li]);   // self row
    int j = 0;
    for (; j + 4 <= deg; j += 4) {
        int b0 = bucket[s0 + j + 0];
        int b1 = bucket[s0 + j + 1];
        int b2 = bucket[s0 + j + 2];
        int b3 = bucket[s0 + j + 3];
        ushort4 r0 = hp[(size_t)b0 * 8 + li];
        ushort4 r1 = hp[(size_t)b1 * 8 + li];
        ushort4 r2 = hp[(size_t)b2 * 8 + li];
        ushort4 r3 = hp[(size_t)b3 * 8 + li];
        float4 v0 = bf4f(r0), v1 = bf4f(r1), v2 = bf4f(r2), v3 = bf4f(r3);
        acc.x += v0.x + v1.x + v2.x + v3.x;
        acc.y += v0.y + v1.y + v2.y + v3.y;
        acc.z += v0.z + v1.z + v2.z + v3.z;
        acc.w += v0.w + v1.w + v2.w + v3.w;
    }
    for (; j < deg; ++j) {
        int b0 = bucket[s0 + j];
        float4 v0 = bf4f(hp[(size_t)b0 * 8 + li]);
        acc.x += v0.x; acc.y += v0.y; acc.z += v0.z; acc.w += v0.w;
    }
    ushort4 u;
    u.x = f2bf(acc.x); u.y = f2bf(acc.y); u.z = f2bf(acc.z); u.w = f2bf(acc.w);
    op[(size_t)i * 8 + li] = u;
}

// ---------------------------------------------------------------------------
// FSTM aggregate (row-major, unchanged): hm[i] = h[i] + sum h[bucket[j]]
// ---------------------------------------------------------------------------
__global__ void aggregate_kernel(const ushort_t* __restrict__ h,
                                 const int* __restrict__ off,
                                 const int* __restrict__ bucket,
                                 ushort_t* __restrict__ hm, int n) {
    int i = blockIdx.x * 4 + (threadIdx.x >> 6);
    if (i >= n) return;
    int lane = threadIdx.x & 63;
    int s0 = off[i], s1 = off[i + 1];
    const ushort4* hp = (const ushort4*)h;   // 64 ushort4 per row
    float4 acc = bf4f(hp[(size_t)i * 64 + lane]);
    int j = s0;
    for (; j + 8 <= s1; j += 8) {
        int bb[8];
#pragma unroll
        for (int q = 0; q < 8; ++q) bb[q] = bucket[j + q];
        ushort4 rr[8];
#pragma unroll
        for (int q = 0; q < 8; ++q) rr[q] = hp[(size_t)bb[q] * 64 + lane];
#pragma unroll
        for (int q = 0; q < 8; ++q) {
            float4 v = bf4f(rr[q]);
            acc.x += v.x; acc.y += v.y; acc.z += v.z; acc.w += v.w;
        }
    }
    for (; j < s1; ++j) {
        float4 v = bf4f(hp[(size_t)bucket[j] * 64 + lane]);
        acc.x += v.x; acc.y += v.y; acc.z += v.z; acc.w += v.w;
    }
    ushort4 u;
    u.x = f2bf(acc.x); u.y = f2bf(acc.y); u.z = f2bf(acc.z); u.w = f2bf(acc.w);
    ((ushort4*)hm)[(size_t)i * 64 + lane] = u;
}

// ---------------------------------------------------------------------------
// tmp[i] = sum_k table[token2nodepos[i,k]+2]   (bf16 table, fp32 accumulate)
// ---------------------------------------------------------------------------
__global__ void tmp_kernel(const ushort_t* __restrict__ gemb,
                           const ushort_t* __restrict__ extra,
                           const int* __restrict__ t2np,
                           ushort_t* __restrict__ D) {
    int i = blockIdx.x * 4 + (threadIdx.x >> 6);
    int lane = threadIdx.x & 63;
    float4 s = make_float4(0.f, 0.f, 0.f, 0.f);
#pragma unroll
    for (int k = 0; k < Kc; ++k) {
        int idx = t2np[i * Kc + k] + 2;
        const ushort4* row = (idx < 2) ? (const ushort4*)(extra + (size_t)idx * Gd)
                                       : (const ushort4*)(gemb + (size_t)(idx - 2) * Gd);
        float4 v = bf4f(row[lane]);
        s.x += v.x; s.y += v.y; s.z += v.z; s.w += v.w;
    }
    ushort4 u;
    u.x = f2bf(s.x); u.y = f2bf(s.y); u.z = f2bf(s.z); u.w = f2bf(s.w);
    ((ushort4*)D)[(size_t)i * 64 + lane] = u;
}

// ---------------------------------------------------------------------------
// row gather (bf16): F[i] = E[ids[i]]
// ---------------------------------------------------------------------------
__global__ void gather_kernel(const ushort_t* __restrict__ Ein,
                              const int* __restrict__ ids,
                              ushort_t* __restrict__ F) {
    int i = blockIdx.x * 4 + (threadIdx.x >> 6);
    int lane = threadIdx.x & 63;
    ((ushort4*)F)[(size_t)i * 64 + lane] =
        ((const ushort4*)Ein)[(size_t)ids[i] * 64 + lane];
}

// ---------------------------------------------------------------------------
// bf16 MFMA GEMM, templated BM x BN (BK=64), lds-dma staging, XCD swizzle,
// T2 source-pre-swizzle bank-conflict fix.
// MODE 0: A = p0[row][k] row-major, rowlen K
// MODE 1: A slice-major [8][M][32]: elem (row,k) at p0[((k>>5)*M+row)*32+(k&31)]
// MODE 2: A = k<256 ? p0 : p1(k-256) rowlen 768        (tmp|text), K=1024
// MODE 3: A = k<768 ? p0 : k<1024 ? p1 : p2            (text|tmp|temporal), K=1280
// OUTBF: 1 -> bf16 C, 0 -> fp32 C.  OUTSM: 1 -> C slice-major [8][M][32]
// ---------------------------------------------------------------------------
#define TBK 64
#define GBM 64
#define GBN 128

__device__ __forceinline__ void xcd_swizzle(int& bx, int& by) {
    int gx = gridDim.x;
    int nwg = gx * gridDim.y;
    int orig = by * gx + bx;
    int q = nwg >> 3, r = nwg & 7;
    int xcd = orig & 7, loc = orig >> 3;
    int wg = (xcd < r ? xcd * (q + 1) : r * (q + 1) + (xcd - r) * q) + loc;
    bx = wg % gx;
    by = wg / gx;
}

template <int MODE, int OUTBF, int OUTSM, int BM, int BN>
__global__ __launch_bounds__(256) void mfma_gemm(
    const ushort_t* __restrict__ p0, const ushort_t* __restrict__ p1,
    const ushort_t* __restrict__ p2, const ushort_t* __restrict__ Wt,
    const float* __restrict__ bias, void* __restrict__ Cv,
    int M, int N, int K, int relu) {
    constexpr int MR = BM / 32;          // m-frags per wave (2 waves in M)
    constexpr int NR = BN / 32;          // n-frags per wave (2 waves in N)
    constexpr int A_IT = (BM * TBK) / 2048;
    constexpr int B_IT = (BN * TBK) / 2048;
    __shared__ ushort_t As[BM * TBK];    // [row][k] linear (lds-dma dest)
    __shared__ ushort_t Bs[BN * TBK];    // [col][k] linear

    int tid  = threadIdx.x;
    int lane = tid & 63;
    int wave = tid >> 6;
    int wm = (wave >> 1) * (BM / 2), wn = (wave & 1) * (BN / 2);
    int bx = blockIdx.x, by = blockIdx.y;
    xcd_swizzle(bx, by);
    int row0 = by * BM, col0 = bx * BN;
    int l15 = lane & 15, l4 = lane >> 4;

    f32x4 acc[MR][NR];
#pragma unroll
    for (int i = 0; i < MR; ++i)
#pragma unroll
        for (int j = 0; j < NR; ++j)
            acc[i][j] = (f32x4){0.f, 0.f, 0.f, 0.f};

    for (int k0 = 0; k0 < K; k0 += TBK) {
        // ---- stage A via lds-dma (pre-swizzled global source) ----
#pragma unroll
        for (int it = 0; it < A_IT; ++it) {
            int eb = it * 2048 + wave * 512;   // wave-uniform elem base
            int le = eb + lane * 8;
            int r  = le >> 6;
            int kl = (le ^ ((r & 7) << 3)) & 63;   // T2 source pre-swizzle (8-aligned)
            int grow = row0 + r; if (grow > M - 1) grow = M - 1;
            int gk = k0 + kl;
            const ushort_t* gp;
            if (MODE == 0)
                gp = p0 + (size_t)grow * K + gk;
            else if (MODE == 1)
                gp = p0 + ((size_t)(gk >> 5) * M + grow) * SLW + (gk & 31);
            else if (MODE == 2)
                gp = (gk < 256) ? p0 + (size_t)grow * 256 + gk
                                : p1 + (size_t)grow * 768 + (gk - 256);
            else
                gp = (gk < 768) ? p0 + (size_t)grow * 768 + gk
                   : (gk < 1024) ? p1 + (size_t)grow * 256 + (gk - 768)
                                 : p2 + (size_t)grow * 256 + (gk - 1024);
            gl2lds16(gp, &As[eb]);
        }
        // ---- stage B via lds-dma ----
#pragma unroll
        for (int it = 0; it < B_IT; ++it) {
            int eb = it * 2048 + wave * 512;
            int le = eb + lane * 8;
            int nl = le >> 6;
            int kl = (le ^ ((nl & 7) << 3)) & 63;
            const ushort_t* gp = Wt + (size_t)(col0 + nl) * K + k0 + kl;
            gl2lds16(gp, &Bs[eb]);
        }
        __syncthreads();

#pragma unroll
        for (int ks = 0; ks < TBK; ks += 32) {
            short8 af[MR], bfr[NR];
#pragma unroll
            for (int mi = 0; mi < MR; ++mi) {
                int row = wm + mi * 16 + l15;
                int col = (ks + l4 * 8) ^ ((row & 7) << 3);
                af[mi] = *(const short8*)&As[row * TBK + col];
            }
#pragma unroll
            for (int ni = 0; ni < NR; ++ni) {
                int row = wn + ni * 16 + l15;
                int col = (ks + l4 * 8) ^ ((row & 7) << 3);
                bfr[ni] = *(const short8*)&Bs[row * TBK + col];
            }
#pragma unroll
            for (int mi = 0; mi < MR; ++mi)
#pragma unroll
                for (int ni = 0; ni < NR; ++ni)
                    acc[mi][ni] = __builtin_amdgcn_mfma_f32_16x16x32_bf16(
                        af[mi], bfr[ni], acc[mi][ni], 0, 0, 0);
        }
        __syncthreads();
    }

    // ---- epilogue: bias (+relu); C/D layout col=lane&15, row=(lane>>4)*4+reg ----
#pragma unroll
    for (int ni = 0; ni < NR; ++ni) {
        int c = col0 + wn + ni * 16 + l15;
        float bv = bias[c];
#pragma unroll
        for (int mi = 0; mi < MR; ++mi) {
#pragma unroll
            for (int r = 0; r < 4; ++r) {
                int rr = row0 + wm + mi * 16 + l4 * 4 + r;
                if (rr < M) {
                    float v = acc[mi][ni][r] + bv;
                    if (relu) v = fmaxf(v, 0.f);
                    if (OUTBF) {
                        if (OUTSM)
                            ((ushort_t*)Cv)[((size_t)(c >> 5) * M + rr) * SLW + (c & 31)] = f2bf(v);
                        else
                            ((ushort_t*)Cv)[(size_t)rr * N + c] = f2bf(v);
                    } else {
                        ((float*)Cv)[(size_t)rr * N + c] = v;
                    }
                }
            }
        }
    }
}

// ---------------------------------------------------------------------------
extern "C" void kernel_launch(void* const* d_in, const int* in_sizes, int n_in,
                              void* d_out, int out_size, void* d_ws, size_t ws_size,
                              hipStream_t stream) {
    const float* text    = (const float*)d_in[0];   // [16384, 768]
    const float* wm_x    = (const float*)d_in[1];   // [50000, 256]
    const int*   wm_ei   = (const int*)d_in[2];     // [2, 800000]
    const int*   t2np    = (const int*)d_in[3];     // [16384, 4]
    const int*   f_ids   = (const int*)d_in[4];     // [16384]
    const int*   f_ei    = (const int*)d_in[5];     // [2, 131072]
    const float* extra   = (const float*)d_in[6];   // [2, 256]
    const float* wm_W1   = (const float*)d_in[7];
    const float* wm_b1   = (const float*)d_in[8];
    const float* wm_W2   = (const float*)d_in[9];
    const float* wm_b2   = (const float*)d_in[10];
    const float* fs_W1   = (const float*)d_in[11];
    const float* fs_b1   = (const float*)d_in[12];
    const float* fs_W2   = (const float*)d_in[13];
    const float* fs_b2   = (const float*)d_in[14];
    const float* fc1_W   = (const float*)d_in[15];  // [1024, 256]
    const float* fc1_b   = (const float*)d_in[16];
    const float* fc3_W   = (const float*)d_in[17];  // [1280, 768]
    const float* fc3_b   = (const float*)d_in[18];
    float* out = (float*)d_out;                     // [16384, 768]

    // ---- workspace layout (bf16 = ushort) ----
    ushort_t* Xb  = (ushort_t*)d_ws;            // [8][50000][32] slice-major (reused: h1)
    ushort_t* Ag  = Xb + 12800000;              // [8][50000][32] aggregate out / scratch
    ushort_t* Gm  = Ag + 12800000;              // [50000*256] gemb row-major (reused: F, H)
    ushort_t* Tx  = Gm + 12800000;              // [16384*768] text bf16
    ushort_t* Dt  = Tx + 12582912;              // [16384*256] tmp
    ushort_t* Ee  = Dt + 4194304;               // [16384*256] gte (reused: T)
    ushort_t* Wv  = Ee + 4194304;               // weights, transposed bf16
    ushort_t* wt_wm1 = Wv;                      //  65536
    ushort_t* wt_wm2 = wt_wm1 + 65536;          //  65536
    ushort_t* wt_fs1 = wt_wm2 + 65536;          //  65536
    ushort_t* wt_fs2 = wt_fs1 + 65536;          //  65536
    ushort_t* wt_fc1 = wt_fs2 + 65536;          //  262144
    ushort_t* wt_fc3 = wt_fc1 + 262144;         //  983040
    ushort_t* Exb    = wt_fc3 + 983040;         //  512
    // persistent CSR outputs
    int* wm_off = (int*)(Exb + 512);            // [N_WM+1]
    int* fs_off = wm_off + N_WM + 1;            // [N_F+1]
    int* wm_bkt = fs_off + N_F + 1;             // [E_WM]
    int* fs_bkt = wm_bkt + E_WM;                // [E_F]
    // CSR-build scratch overlaid on Ag (dead until first aggregate)
    int2* SEwm = (int2*)Ag;                     // [E_WM] int2 (6.4MB)
    int2* SEfs = SEwm + E_WM;                   // [E_F]  int2 (1.05MB)
    int*  Cwm  = (int*)(SEfs + E_F);            // [WM_P*256]
    int*  Cfs  = Cwm + WM_P * 256;              // [FS_P*256]
    int*  BTwm = Cfs + FS_P * 256;              // [256]
    int*  BTfs = BTwm + 256;                    // [256]
    int*  BSwm = BTfs + 256;                    // [257]
    int*  BSfs = BSwm + 257;                    // [257]

    ushort_t* h1 = Xb;                 // gemm1 out overwrites Xb (dead), slice-major
    ushort_t* F  = Gm;                 // gather out overwrites gemb (dead)
    ushort_t* H  = Gm + 4194304;
    ushort_t* T  = Ee;                 // fstm out overwrites Ee (dead)

    const int* wm_src = wm_ei;
    const int* wm_dst = wm_ei + E_WM;
    const int* f_src  = f_ei;
    const int* f_dst  = f_ei + E_F;

    dim3 blk(256);
    dim3 gW(Gd / GBN, (N_WM + GBM - 1) / GBM);   // 2 x 782
    dim3 gF(Gd / GBN, N_F / GBM);                // 2 x 256
    dim3 gO(PLM / GBN, N_F / GBM);               // 6 x 256
    const int gAggW = NSL * ((N_WM + 31) / 32);  // 8 x 1563 = 12504 (32 nodes/block)

    // ===== CSR build (counting sort, LDS atomics only) =====
    csr_p1<<<WM_P + FS_P, blk, 0, stream>>>(wm_dst, f_dst, Cwm, Cfs);
    csr_p2a<<<512, blk, 0, stream>>>(Cwm, BTwm, Cfs, BTfs);
    csr_p2b<<<2, blk, 0, stream>>>(BTwm, BSwm, BTfs, BSfs);
    csr_p3<<<WM_P + FS_P, blk, 0, stream>>>(wm_src, wm_dst, Cwm, BSwm, SEwm,
                                            f_src, f_dst, Cfs, BSfs, SEfs);
    csr_p4<<<512, blk, 0, stream>>>(SEwm, BSwm, wm_off, wm_bkt,
                                    SEfs, BSfs, fs_off, fs_bkt);

    // ===== one-time conversions (fused) =====
    conv_all<<<25157, blk, 0, stream>>>(wm_x, text, extra,
                                        wm_W1, wm_W2, fs_W1, fs_W2, fc1_W, fc3_W,
                                        Xb, Tx, Exb,
                                        wt_wm1, wt_wm2, wt_fs1, wt_fs2,
                                        wt_fc1, wt_fc3);

    // ===== WM layer 1 (slice-major path) =====
    aggregate_sliced<<<gAggW, blk, 0, stream>>>(Xb, wm_off, wm_bkt, Ag, N_WM);
    mfma_gemm<1, 1, 1, GBM, GBN><<<gW, blk, 0, stream>>>(Ag, nullptr, nullptr, wt_wm1,
                                                         wm_b1, h1, N_WM, Gd, Gd, 1);
    // ===== WM layer 2 =====
    aggregate_sliced<<<gAggW, blk, 0, stream>>>(h1, wm_off, wm_bkt, Ag, N_WM);
    mfma_gemm<1, 1, 0, GBM, GBN><<<gW, blk, 0, stream>>>(Ag, nullptr, nullptr, wt_wm2,
                                                         wm_b2, Gm, N_WM, Gd, Gd, 1);
    // ===== tmp =====
    tmp_kernel<<<N_F / 4, blk, 0, stream>>>(Gm, Exb, t2np, Dt);
    // ===== fc1: Ee = concat(tmp, text) @ fc1_W + b =====
    mfma_gemm<2, 1, 0, GBM, GBN><<<gF, blk, 0, stream>>>(Dt, Tx, nullptr, wt_fc1,
                                                         fc1_b, Ee, N_F, Gd, Gd + PLM, 0);
    // ===== FSTM gather =====
    gather_kernel<<<N_F / 4, blk, 0, stream>>>(Ee, f_ids, F);
    // ===== FSTM layer 1 (row-major path) =====
    aggregate_kernel<<<N_F / 4, blk, 0, stream>>>(F, fs_off, fs_bkt, Ag, N_F);
    mfma_gemm<0, 1, 0, GBM, GBN><<<gF, blk, 0, stream>>>(Ag, nullptr, nullptr, wt_fs1,
                                                         fs_b1, H, N_F, Gd, Gd, 1);
    // ===== FSTM layer 2 =====
    aggregate_kernel<<<N_F / 4, blk, 0, stream>>>(H, fs_off, fs_bkt, Ag, N_F);
    mfma_gemm<0, 1, 0, GBM, GBN><<<gF, blk, 0, stream>>>(Ag, nullptr, nullptr, wt_fs2,
                                                         fs_b2, T, N_F, Gd, Gd, 1);
    // ===== fc3: out = concat(text, tmp, temporal) @ fc3_W + b (fp32 out) =====
    mfma_gemm<3, 0, 0, GBM, GBN><<<gO, blk, 0, stream>>>(Tx, Dt, T, wt_fc3, fc3_b,
                                                         out, N_F, PLM, PLM + 2 * Gd, 0);
}